// Round 1
// baseline (1474.189 us; speedup 1.0000x reference)
//
#include <hip/hip_runtime.h>

// Instant-NGP style hash-grid encoder.
// N=1048576 points, 16 levels, LEVEL_DIM=2, HASHMAP_SIZE=2^19, BASE_RES=16.
//
// Hash identity used: table index = ((cx*P0 + cy*P1 + cz*P2) & (2^19-1)) ^ lvl
// computed entirely in uint32 (low 19 bits of products/sums are exact under
// 32-bit wraparound; corners are non-negative; lvl < 16 so XOR commutes with
// the low-19-bit mask).

#define NUM_LEVELS 16
#define HASHMAP_SIZE (1u << 19)
#define HASH_MASK (HASHMAP_SIZE - 1u)
#define BASE_RES 16

__global__ __launch_bounds__(256) void hash_encode_kernel(
    const float* __restrict__ x,       // [N,3]
    const float* __restrict__ tables,  // [16, 2^19, 2]
    float* __restrict__ out,           // [N,32]
    int n) {
  const int i = blockIdx.x * blockDim.x + threadIdx.x;
  if (i >= n) return;

  const unsigned P0 = 1546061u, P1 = 1005013u, P2 = 1673733u;
  const float UB = (float)(1.0 - 1e-6);  // matches jnp.clip upper bound

  // load point (12B per thread)
  const float px = x[3 * (size_t)i + 0];
  const float py = x[3 * (size_t)i + 1];
  const float pz = x[3 * (size_t)i + 2];

  // normalize to [0, 1): (x + 1) / 2, clipped
  const float xn0 = fminf(fmaxf((px + 1.0f) * 0.5f, 0.0f), UB);
  const float xn1 = fminf(fmaxf((py + 1.0f) * 0.5f, 0.0f), UB);
  const float xn2 = fminf(fmaxf((pz + 1.0f) * 0.5f, 0.0f), UB);

  float outv[2 * NUM_LEVELS];

#pragma unroll
  for (int lvl = 0; lvl < NUM_LEVELS; ++lvl) {
    const float res = (float)(BASE_RES << lvl);
    const float s0 = xn0 * res;
    const float s1 = xn1 * res;
    const float s2 = xn2 * res;
    const float f0 = floorf(s0);
    const float f1 = floorf(s1);
    const float f2 = floorf(s2);
    const float fr0 = s0 - f0;
    const float fr1 = s1 - f1;
    const float fr2 = s2 - f2;
    const unsigned c0 = (unsigned)f0;
    const unsigned c1 = (unsigned)f1;
    const unsigned c2 = (unsigned)f2;

    const unsigned base = c0 * P0 + c1 * P1 + c2 * P2;  // uint32 wrap OK
    const float2* __restrict__ tbl =
        (const float2*)(tables + (size_t)lvl * HASHMAP_SIZE * 2);

    const float g0 = 1.0f - fr0, g1 = 1.0f - fr1, g2 = 1.0f - fr2;

    float acc0 = 0.0f, acc1 = 0.0f;
#pragma unroll
    for (int corner = 0; corner < 8; ++corner) {
      unsigned h = base;
      float w = 1.0f;
      if (corner & 4) { h += P0; w *= fr0; } else { w *= g0; }
      if (corner & 2) { h += P1; w *= fr1; } else { w *= g1; }
      if (corner & 1) { h += P2; w *= fr2; } else { w *= g2; }
      h = (h & HASH_MASK) ^ (unsigned)lvl;
      const float2 e = tbl[h];
      acc0 += e.x * w;
      acc1 += e.y * w;
    }
    outv[2 * lvl + 0] = acc0;
    outv[2 * lvl + 1] = acc1;
  }

  // store 32 floats as 8x float4 (128B per thread)
  float4* o = (float4*)(out + (size_t)i * (2 * NUM_LEVELS));
#pragma unroll
  for (int k = 0; k < 8; ++k) {
    o[k] = ((const float4*)outv)[k];
  }
}

extern "C" void kernel_launch(void* const* d_in, const int* in_sizes, int n_in,
                              void* d_out, int out_size, void* d_ws, size_t ws_size,
                              hipStream_t stream) {
  const float* x = (const float*)d_in[0];
  const float* tables = (const float*)d_in[1];
  float* out = (float*)d_out;
  const int n = in_sizes[0] / 3;  // N points

  const int block = 256;
  const int grid = (n + block - 1) / block;
  hash_encode_kernel<<<grid, block, 0, stream>>>(x, tables, out, n);
}

// Round 2
// 655.203 us; speedup vs baseline: 2.2500x; 2.2500x over previous
//
#include <hip/hip_runtime.h>

// Instant-NGP style hash-grid encoder, level-partitioned for L2 locality.
// N=1048576 points, 16 levels, LEVEL_DIM=2, HASHMAP_SIZE=2^19, BASE_RES=16.
//
// Hash identity: idx = ((cx*P0 + cy*P1 + cz*P2) & (2^19-1)) ^ lvl, computed in
// uint32 (low 19 bits exact under 32-bit wraparound; corners >= 0; lvl < 16).
//
// Round-2 structure: each block processes ONE level for a 256-point chunk.
// blockIdx swizzle puts level L's blocks on XCD L%8 (round-robin wg->XCD),
// with L/8 slowest, so each XCD's 4 MiB L2 holds exactly its one 4 MiB table.
// Kernel 1 writes level-major ws[16][N][2] (coalesced, nontemporal to keep
// tables L2-resident); kernel 2 transposes to out[N][32].

#define NUM_LEVELS 16
#define HASHMAP_SIZE (1u << 19)
#define HASH_MASK (HASHMAP_SIZE - 1u)
#define BASE_RES 16
#define NXCD 8

template <bool DIRECT>
__global__ __launch_bounds__(256) void hash_level_kernel(
    const float* __restrict__ x,       // [N,3]
    const float* __restrict__ tables,  // [16, 2^19, 2]
    float* __restrict__ dst,           // DIRECT ? out[N,32] : ws[16,N,2]
    int n, int nchunk) {
  // decode swizzled block id -> (lvl, chunk)
  const int b = blockIdx.x;
  const int lvl_lo = b % NXCD;
  const int r = b / NXCD;
  const int chunk = r % nchunk;
  const int lvl_hi = r / nchunk;
  const int lvl = lvl_lo + NXCD * lvl_hi;

  const int i = chunk * 256 + (int)threadIdx.x;
  if (i >= n) return;

  const unsigned P0 = 1546061u, P1 = 1005013u, P2 = 1673733u;
  const float UB = (float)(1.0 - 1e-6);

  const float px = x[3 * (size_t)i + 0];
  const float py = x[3 * (size_t)i + 1];
  const float pz = x[3 * (size_t)i + 2];

  const float xn0 = fminf(fmaxf((px + 1.0f) * 0.5f, 0.0f), UB);
  const float xn1 = fminf(fmaxf((py + 1.0f) * 0.5f, 0.0f), UB);
  const float xn2 = fminf(fmaxf((pz + 1.0f) * 0.5f, 0.0f), UB);

  const float res = (float)(BASE_RES << lvl);
  const float s0 = xn0 * res;
  const float s1 = xn1 * res;
  const float s2 = xn2 * res;
  const float f0 = floorf(s0);
  const float f1 = floorf(s1);
  const float f2 = floorf(s2);
  const float fr0 = s0 - f0, fr1 = s1 - f1, fr2 = s2 - f2;
  const unsigned c0 = (unsigned)f0, c1 = (unsigned)f1, c2 = (unsigned)f2;

  const unsigned base = c0 * P0 + c1 * P1 + c2 * P2;  // uint32 wrap OK
  const float2* __restrict__ tbl =
      (const float2*)(tables + (size_t)lvl * HASHMAP_SIZE * 2);
  const float g0 = 1.0f - fr0, g1 = 1.0f - fr1, g2 = 1.0f - fr2;

  float acc0 = 0.0f, acc1 = 0.0f;
#pragma unroll
  for (int corner = 0; corner < 8; ++corner) {
    unsigned h = base;
    float w = 1.0f;
    if (corner & 4) { h += P0; w *= fr0; } else { w *= g0; }
    if (corner & 2) { h += P1; w *= fr1; } else { w *= g1; }
    if (corner & 1) { h += P2; w *= fr2; } else { w *= g2; }
    h = (h & HASH_MASK) ^ (unsigned)lvl;
    const float2 e = tbl[h];
    acc0 += e.x * w;
    acc1 += e.y * w;
  }

  if (DIRECT) {
    // strided 8B write into out[N,32] (fallback path)
    float2* o = (float2*)(dst + (size_t)i * (2 * NUM_LEVELS) + 2 * lvl);
    *o = make_float2(acc0, acc1);
  } else {
    // coalesced level-major write, nontemporal (don't evict tables from L2)
    float2 v = make_float2(acc0, acc1);
    double* p = (double*)(dst + ((size_t)lvl * n + i) * 2);
    __builtin_nontemporal_store(*(const double*)&v, p);
  }
}

__global__ __launch_bounds__(256) void transpose_kernel(
    const float* __restrict__ ws,  // [16, N, 2]
    float* __restrict__ out,       // [N, 32]
    int n) {
  const int i = blockIdx.x * blockDim.x + threadIdx.x;
  if (i >= n) return;

  float outv[2 * NUM_LEVELS];
#pragma unroll
  for (int lvl = 0; lvl < NUM_LEVELS; ++lvl) {
    const double* p = (const double*)(ws + ((size_t)lvl * n + i) * 2);
    double d = __builtin_nontemporal_load(p);
    ((double*)outv)[lvl] = d;
  }
  float4* o = (float4*)(out + (size_t)i * (2 * NUM_LEVELS));
#pragma unroll
  for (int k = 0; k < 8; ++k) o[k] = ((const float4*)outv)[k];
}

extern "C" void kernel_launch(void* const* d_in, const int* in_sizes, int n_in,
                              void* d_out, int out_size, void* d_ws, size_t ws_size,
                              hipStream_t stream) {
  const float* x = (const float*)d_in[0];
  const float* tables = (const float*)d_in[1];
  float* out = (float*)d_out;
  const int n = in_sizes[0] / 3;  // N points

  const int block = 256;
  const int nchunk = (n + block - 1) / block;
  const int nblocks = nchunk * NUM_LEVELS;

  const size_t ws_needed = (size_t)NUM_LEVELS * n * 2 * sizeof(float);
  if (ws_size >= ws_needed) {
    float* ws = (float*)d_ws;
    hash_level_kernel<false><<<nblocks, block, 0, stream>>>(x, tables, ws, n, nchunk);
    transpose_kernel<<<nchunk, block, 0, stream>>>(ws, out, n);
  } else {
    hash_level_kernel<true><<<nblocks, block, 0, stream>>>(x, tables, out, n, nchunk);
  }
}